// Round 9
// baseline (2094.198 us; speedup 1.0000x reference)
//
#include <hip/hip_runtime.h>
#include <hip/hip_bf16.h>
#include <math.h>

// ---------------- problem constants ----------------
constexpr int T_STEPS = 256;
constexpr int HDIM    = 1024;
constexpr int EDIM    = 512;
constexpr int VDIM    = 32000;

#define RG     128          // recurrence workgroups (spread over chip, 1/CU)
#define RROWS  8            // rows owned per WG

// ---------------- ws layout (float offsets) ----------------
// Overlays (proven by publish-chain ordering): hseq fp32 over BZ, hseq bf16 over BR.
constexpr size_t WS_BZ     = 0;                                   // [T][H]
constexpr size_t WS_BR     = WS_BZ + (size_t)T_STEPS * HDIM;      // [T][H]
constexpr size_t WS_A      = WS_BR + (size_t)T_STEPS * HDIM;      // [T][H]
constexpr size_t WS_HPACK  = WS_A  + (size_t)T_STEPS * HDIM;      // ull[(T+1)][H]: (tag<<32)|bits
constexpr size_t WS_RHPACK = WS_HPACK + (size_t)2 * (T_STEPS + 1) * HDIM; // ull[H]
constexpr size_t WS_HSEQ   = WS_BZ;                               // fp32 overlay
constexpr size_t WS_HSEQB  = WS_BR;                               // bf16 overlay (ushort*)

typedef __attribute__((ext_vector_type(8))) short short8;
typedef __attribute__((ext_vector_type(4))) float f32x4;

__device__ __forceinline__ float sigmoidf_(float x) { return 1.0f / (1.0f + __expf(-x)); }

__device__ __forceinline__ unsigned long long pack_tv(int tag, float v) {
  return ((unsigned long long)(unsigned)tag << 32) | (unsigned long long)__float_as_uint(v);
}

__device__ __forceinline__ unsigned short f2bf(float f) {   // RNE fp32 -> bf16 bits (manual)
  unsigned u = __float_as_uint(f);
  return (unsigned short)((u + 0x7FFFu + ((u >> 16) & 1u)) >> 16);
}

__device__ __forceinline__ unsigned short f2bf_fast(float f) {  // compiler-fusable RNE cast
  __hip_bfloat16 b = __float2bfloat16(f);
  return *reinterpret_cast<unsigned short*>(&b);
}

// ---------------- 3-deep pipelined poll, fully inside ONE asm block ----------------
// Polls 4 consecutive ull words at p until every lane's 4 tags == ex (range check:
// exl <= w < exh, i.e. high dword == tag). 12 loads in flight -> sample period ~ L/3.
// r8 lesson: pending-load registers must NEVER cross compiler-visible control flow —
// the whole wait/check/reissue loop lives in this single block; vmcnt drained at exit.
__device__ __forceinline__ void poll4_fast(const unsigned long long* p,
                                           unsigned long long exl, unsigned long long exh,
                                           unsigned long long& o0, unsigned long long& o1,
                                           unsigned long long& o2, unsigned long long& o3) {
  unsigned long long a0, a1, a2, a3, b0, b1, b2, b3, c0, c1, c2, c3, ac;
  int fl, ct;
  asm volatile(
    "s_waitcnt vmcnt(0)\n\t"                                   // clean vmcnt baseline
    "s_mov_b32 %[fl], 0\n\t"
    "s_mov_b32 %[ct], 0\n\t"
    "global_load_dwordx2 %[a0], %[p], off sc0 sc1\n\t"         // batch A
    "global_load_dwordx2 %[a1], %[p], off offset:8 sc0 sc1\n\t"
    "global_load_dwordx2 %[a2], %[p], off offset:16 sc0 sc1\n\t"
    "global_load_dwordx2 %[a3], %[p], off offset:24 sc0 sc1\n\t"
    "global_load_dwordx2 %[b0], %[p], off sc0 sc1\n\t"         // batch B
    "global_load_dwordx2 %[b1], %[p], off offset:8 sc0 sc1\n\t"
    "global_load_dwordx2 %[b2], %[p], off offset:16 sc0 sc1\n\t"
    "global_load_dwordx2 %[b3], %[p], off offset:24 sc0 sc1\n\t"
    "global_load_dwordx2 %[c0], %[p], off sc0 sc1\n\t"         // batch C
    "global_load_dwordx2 %[c1], %[p], off offset:8 sc0 sc1\n\t"
    "global_load_dwordx2 %[c2], %[p], off offset:16 sc0 sc1\n\t"
    "global_load_dwordx2 %[c3], %[p], off offset:24 sc0 sc1\n"
    "PL%=:\n\t"
    "s_waitcnt vmcnt(8)\n\t"                                   // oldest batch (A) landed
    "v_cmp_le_u64 vcc, %[el], %[a0]\n\t"
    "s_mov_b64 %[ac], vcc\n\t"
    "v_cmp_gt_u64 vcc, %[eh], %[a0]\n\t"
    "s_and_b64 %[ac], %[ac], vcc\n\t"
    "v_cmp_le_u64 vcc, %[el], %[a1]\n\t"
    "s_and_b64 %[ac], %[ac], vcc\n\t"
    "v_cmp_gt_u64 vcc, %[eh], %[a1]\n\t"
    "s_and_b64 %[ac], %[ac], vcc\n\t"
    "v_cmp_le_u64 vcc, %[el], %[a2]\n\t"
    "s_and_b64 %[ac], %[ac], vcc\n\t"
    "v_cmp_gt_u64 vcc, %[eh], %[a2]\n\t"
    "s_and_b64 %[ac], %[ac], vcc\n\t"
    "v_cmp_le_u64 vcc, %[el], %[a3]\n\t"
    "s_and_b64 %[ac], %[ac], vcc\n\t"
    "v_cmp_gt_u64 vcc, %[eh], %[a3]\n\t"
    "s_and_b64 %[ac], %[ac], vcc\n\t"
    "s_andn2_b64 %[ac], exec, %[ac]\n\t"                       // SCC = (not-ready lanes != 0)
    "s_cbranch_scc0 DA%=\n\t"
    "s_addk_i32 %[ct], 1\n\t"
    "s_cmp_gt_u32 %[ct], 8192\n\t"
    "s_cbranch_scc1 DA%=\n\t"                                  // valve: bounded garbage, no hang
    "s_sleep 1\n\t"
    "global_load_dwordx2 %[a0], %[p], off sc0 sc1\n\t"         // reissue A
    "global_load_dwordx2 %[a1], %[p], off offset:8 sc0 sc1\n\t"
    "global_load_dwordx2 %[a2], %[p], off offset:16 sc0 sc1\n\t"
    "global_load_dwordx2 %[a3], %[p], off offset:24 sc0 sc1\n\t"
    "s_waitcnt vmcnt(8)\n\t"                                   // B landed
    "v_cmp_le_u64 vcc, %[el], %[b0]\n\t"
    "s_mov_b64 %[ac], vcc\n\t"
    "v_cmp_gt_u64 vcc, %[eh], %[b0]\n\t"
    "s_and_b64 %[ac], %[ac], vcc\n\t"
    "v_cmp_le_u64 vcc, %[el], %[b1]\n\t"
    "s_and_b64 %[ac], %[ac], vcc\n\t"
    "v_cmp_gt_u64 vcc, %[eh], %[b1]\n\t"
    "s_and_b64 %[ac], %[ac], vcc\n\t"
    "v_cmp_le_u64 vcc, %[el], %[b2]\n\t"
    "s_and_b64 %[ac], %[ac], vcc\n\t"
    "v_cmp_gt_u64 vcc, %[eh], %[b2]\n\t"
    "s_and_b64 %[ac], %[ac], vcc\n\t"
    "v_cmp_le_u64 vcc, %[el], %[b3]\n\t"
    "s_and_b64 %[ac], %[ac], vcc\n\t"
    "v_cmp_gt_u64 vcc, %[eh], %[b3]\n\t"
    "s_and_b64 %[ac], %[ac], vcc\n\t"
    "s_andn2_b64 %[ac], exec, %[ac]\n\t"
    "s_cbranch_scc0 DB%=\n\t"
    "s_addk_i32 %[ct], 1\n\t"
    "s_cmp_gt_u32 %[ct], 8192\n\t"
    "s_cbranch_scc1 DB%=\n\t"
    "s_sleep 1\n\t"
    "global_load_dwordx2 %[b0], %[p], off sc0 sc1\n\t"         // reissue B
    "global_load_dwordx2 %[b1], %[p], off offset:8 sc0 sc1\n\t"
    "global_load_dwordx2 %[b2], %[p], off offset:16 sc0 sc1\n\t"
    "global_load_dwordx2 %[b3], %[p], off offset:24 sc0 sc1\n\t"
    "s_waitcnt vmcnt(8)\n\t"                                   // C landed
    "v_cmp_le_u64 vcc, %[el], %[c0]\n\t"
    "s_mov_b64 %[ac], vcc\n\t"
    "v_cmp_gt_u64 vcc, %[eh], %[c0]\n\t"
    "s_and_b64 %[ac], %[ac], vcc\n\t"
    "v_cmp_le_u64 vcc, %[el], %[c1]\n\t"
    "s_and_b64 %[ac], %[ac], vcc\n\t"
    "v_cmp_gt_u64 vcc, %[eh], %[c1]\n\t"
    "s_and_b64 %[ac], %[ac], vcc\n\t"
    "v_cmp_le_u64 vcc, %[el], %[c2]\n\t"
    "s_and_b64 %[ac], %[ac], vcc\n\t"
    "v_cmp_gt_u64 vcc, %[eh], %[c2]\n\t"
    "s_and_b64 %[ac], %[ac], vcc\n\t"
    "v_cmp_le_u64 vcc, %[el], %[c3]\n\t"
    "s_and_b64 %[ac], %[ac], vcc\n\t"
    "v_cmp_gt_u64 vcc, %[eh], %[c3]\n\t"
    "s_and_b64 %[ac], %[ac], vcc\n\t"
    "s_andn2_b64 %[ac], exec, %[ac]\n\t"
    "s_cbranch_scc0 DC%=\n\t"
    "s_addk_i32 %[ct], 1\n\t"
    "s_cmp_gt_u32 %[ct], 8192\n\t"
    "s_cbranch_scc1 DC%=\n\t"
    "s_sleep 1\n\t"
    "global_load_dwordx2 %[c0], %[p], off sc0 sc1\n\t"         // reissue C
    "global_load_dwordx2 %[c1], %[p], off offset:8 sc0 sc1\n\t"
    "global_load_dwordx2 %[c2], %[p], off offset:16 sc0 sc1\n\t"
    "global_load_dwordx2 %[c3], %[p], off offset:24 sc0 sc1\n\t"
    "s_branch PL%=\n"
    "DC%=:\n\t"
    "s_mov_b32 %[fl], 2\n\t"
    "s_branch DR%=\n"
    "DB%=:\n\t"
    "s_mov_b32 %[fl], 1\n"
    "DR%=:\n"
    "DA%=:\n\t"
    "s_waitcnt vmcnt(0)"                                       // no pending reg escapes
    : [a0]"=&v"(a0), [a1]"=&v"(a1), [a2]"=&v"(a2), [a3]"=&v"(a3),
      [b0]"=&v"(b0), [b1]"=&v"(b1), [b2]"=&v"(b2), [b3]"=&v"(b3),
      [c0]"=&v"(c0), [c1]"=&v"(c1), [c2]"=&v"(c2), [c3]"=&v"(c3),
      [ac]"=&s"(ac), [fl]"=&s"(fl), [ct]"=&s"(ct)
    : [p]"v"(p), [el]"s"(exl), [eh]"s"(exh)
    : "vcc", "scc", "memory");
  if (fl == 1)      { o0 = b0; o1 = b1; o2 = b2; o3 = b3; }
  else if (fl == 2) { o0 = c0; o1 = c1; o2 = c2; o3 = c3; }
  else              { o0 = a0; o1 = a1; o2 = a2; o3 = a3; }
}

// ---------------- init: clear tags (ws NOT re-poisoned between replays), pack h0 ----------------
__global__ __launch_bounds__(256) void k_init(const float* __restrict__ enc, float* __restrict__ ws) {
  unsigned long long* hpack  = (unsigned long long*)(ws + WS_HPACK);
  unsigned long long* rhpack = (unsigned long long*)(ws + WS_RHPACK);
  const int b = blockIdx.x, tid = threadIdx.x;
  if (b == 0) {
    for (int i = tid; i < HDIM; i += 256) hpack[i] = pack_tv(1, enc[i]);
  } else if (b <= T_STEPS) {
    unsigned long long* row = hpack + (size_t)b * HDIM;
    for (int i = tid; i < HDIM; i += 256) row[i] = 0ULL;
  } else {
    for (int i = tid; i < HDIM; i += 256) rhpack[i] = 0ULL;
  }
}

// ---------------- batched e-projections: Bz/Br/A for all t ----------------
__global__ __launch_bounds__(256) void k_xproj(
    const int* __restrict__ tokens, const float* __restrict__ emb,
    const float* __restrict__ wzx, const float* __restrict__ wrx, const float* __restrict__ whx,
    const float* __restrict__ bzx, const float* __restrict__ bzh,
    const float* __restrict__ brx, const float* __restrict__ brh,
    const float* __restrict__ bhx, const float* __restrict__ bhh,
    float* __restrict__ ws) {
  __shared__ __align__(16) float es[16][EDIM];   // 32 KiB
  const int b   = blockIdx.x;
  const int t0  = (b & 15) * 16;
  const int c   = b >> 4;                 // 0..11
  const int tid = threadIdx.x;

  {
    int row = tid >> 4;
    int kc  = (tid & 15) * 32;
    int tok = tokens[t0 + row];
    const float4* ep = (const float4*)(emb + (size_t)tok * EDIM + kc);
    float4* dst = (float4*)&es[row][kc];
    #pragma unroll
    for (int q = 0; q < 8; q++) dst[q] = ep[q];
  }
  __syncthreads();

  const int mat = c >> 2;
  const int j   = (c & 3) * 256 + tid;
  const float* W; const float* b1; const float* b2; float* Xout;
  if (mat == 0)      { W = wzx; b1 = bzx; b2 = bzh; Xout = ws + WS_BZ; }
  else if (mat == 1) { W = wrx; b1 = brx; b2 = brh; Xout = ws + WS_BR; }
  else               { W = whx; b1 = bhx; b2 = bhh; Xout = ws + WS_A;  }

  const float4* wp = (const float4*)(W + (size_t)j * EDIM);
  const float bias = b1[j] + b2[j];
  float acc[16];
  #pragma unroll
  for (int tt = 0; tt < 16; tt++) acc[tt] = 0.0f;

  for (int k4 = 0; k4 < EDIM / 4; k4++) {
    float4 w = wp[k4];
    #pragma unroll
    for (int tt = 0; tt < 16; tt++) {
      float4 e4 = *(const float4*)&es[tt][k4 * 4];
      acc[tt] += w.x * e4.x + w.y * e4.y + w.z * e4.z + w.w * e4.w;
    }
  }
  #pragma unroll
  for (int tt = 0; tt < 16; tt++)
    Xout[(size_t)(t0 + tt) * HDIM + j] = acc[tt] + bias;
}

// ---------------- persistent GRU recurrence (r3 structure; 3-deep pipelined polls) ----------------
__global__ __launch_bounds__(256) void k_recur(
    const float* __restrict__ wzh, const float* __restrict__ wrh, const float* __restrict__ whh,
    float* __restrict__ ws) {
  const int g    = blockIdx.x;
  const int tid  = threadIdx.x;
  const int lane = tid & 63;
  const int wv   = tid >> 6;
  const float* Bz = ws + WS_BZ;
  const float* Br = ws + WS_BR;
  const float* Aa = ws + WS_A;
  float* hseq = ws + WS_HSEQ;
  unsigned short* hseqb = (unsigned short*)(ws + WS_HSEQB);
  unsigned long long* hpack  = (unsigned long long*)(ws + WS_HPACK);
  unsigned long long* rhpack = (unsigned long long*)(ws + WS_RHPACK);

  const int j0 = 4 * tid;          // this thread's h-slice [j0, j0+4) — single producer WG
  const int r0 = g * RROWS;        // this WG's row base

  // register-resident weights: 3 x 8 rows x 4 cols = 96 floats
  float4 wz[RROWS], wr[RROWS], wh[RROWS];
  #pragma unroll
  for (int k = 0; k < RROWS; k++) {
    wz[k] = *(const float4*)(wzh + (size_t)(r0 + k) * HDIM + j0);
    wr[k] = *(const float4*)(wrh + (size_t)(r0 + k) * HDIM + j0);
    wh[k] = *(const float4*)(whh + (size_t)(r0 + k) * HDIM + j0);
  }

  __shared__ float redA[4][2 * RROWS];   // round A (z | r); separate from round B
  __shared__ float redB[4][RROWS];
  __shared__ float zs[RROWS];
  __shared__ float hloc[RROWS];
  if (tid < RROWS)
    hloc[tid] = __uint_as_float((unsigned)hpack[r0 + tid]);  // h0, written by k_init
  __syncthreads();

  for (int t = 0; t < T_STEPS; t++) {
    float bz_pre = 0.0f, br_pre = 0.0f, a_pre = 0.0f;
    if (tid < RROWS) {
      bz_pre = Bz[(size_t)t * HDIM + r0 + tid];
      a_pre  = Aa[(size_t)t * HDIM + r0 + tid];
    } else if (tid < 2 * RROWS) {
      br_pre = Br[(size_t)t * HDIM + r0 + (tid - RROWS)];
    }
    const unsigned long long exl = ((unsigned long long)(unsigned)(t + 1)) << 32;
    const unsigned long long exh = ((unsigned long long)(unsigned)(t + 2)) << 32;

    // ================= round A: z, r, publish r*h =================
    float hv0, hv1, hv2, hv3;
    {
      unsigned long long w0, w1, w2, w3;
      poll4_fast(hpack + (size_t)t * HDIM + j0, exl, exh, w0, w1, w2, w3);
      hv0 = __uint_as_float((unsigned)w0);
      hv1 = __uint_as_float((unsigned)w1);
      hv2 = __uint_as_float((unsigned)w2);
      hv3 = __uint_as_float((unsigned)w3);
    }

    float pz[RROWS], pr[RROWS];
    #pragma unroll
    for (int k = 0; k < RROWS; k++) {
      pz[k] = wz[k].x * hv0 + wz[k].y * hv1 + wz[k].z * hv2 + wz[k].w * hv3;
      pr[k] = wr[k].x * hv0 + wr[k].y * hv1 + wr[k].z * hv2 + wr[k].w * hv3;
    }
    #pragma unroll
    for (int m = 32; m >= 1; m >>= 1) {
      #pragma unroll
      for (int k = 0; k < RROWS; k++) {
        pz[k] += __shfl_xor(pz[k], m);
        pr[k] += __shfl_xor(pr[k], m);
      }
    }
    if (lane == 0) {
      #pragma unroll
      for (int k = 0; k < RROWS; k++) { redA[wv][k] = pz[k]; redA[wv][RROWS + k] = pr[k]; }
    }
    __syncthreads();
    if (tid < RROWS) {
      float u = redA[0][tid] + redA[1][tid] + redA[2][tid] + redA[3][tid];
      zs[tid] = sigmoidf_(bz_pre + u);
    } else if (tid < 2 * RROWS) {
      int k = tid - RROWS;
      float u = redA[0][tid] + redA[1][tid] + redA[2][tid] + redA[3][tid];
      float r = sigmoidf_(br_pre + u);
      float rh = r * hloc[k];
      __hip_atomic_store(&rhpack[r0 + k], pack_tv(t + 1, rh),
                         __ATOMIC_RELAXED, __HIP_MEMORY_SCOPE_AGENT);
    }

    // ================= round B: v = whh@(r*h), h_new =================
    float rv0, rv1, rv2, rv3;
    {
      unsigned long long w0, w1, w2, w3;
      poll4_fast(rhpack + j0, exl, exh, w0, w1, w2, w3);
      rv0 = __uint_as_float((unsigned)w0);
      rv1 = __uint_as_float((unsigned)w1);
      rv2 = __uint_as_float((unsigned)w2);
      rv3 = __uint_as_float((unsigned)w3);
    }

    float ph[RROWS];
    #pragma unroll
    for (int k = 0; k < RROWS; k++)
      ph[k] = wh[k].x * rv0 + wh[k].y * rv1 + wh[k].z * rv2 + wh[k].w * rv3;
    #pragma unroll
    for (int m = 32; m >= 1; m >>= 1) {
      #pragma unroll
      for (int k = 0; k < RROWS; k++) ph[k] += __shfl_xor(ph[k], m);
    }
    if (lane == 0) {
      #pragma unroll
      for (int k = 0; k < RROWS; k++) redB[wv][k] = ph[k];
    }
    __syncthreads();
    if (tid < RROWS) {
      float v  = redB[0][tid] + redB[1][tid] + redB[2][tid] + redB[3][tid];
      float z  = zs[tid];
      float hk = hloc[tid];
      float hp_ = tanhf(a_pre + v);
      float hn = (1.0f - z) * hk + z * hp_;
      hloc[tid] = hn;
      __hip_atomic_store(&hpack[(size_t)(t + 1) * HDIM + r0 + tid], pack_tv(t + 2, hn),
                         __ATOMIC_RELAXED, __HIP_MEMORY_SCOPE_AGENT);
      hseq[(size_t)t * HDIM + r0 + tid] = hn;               // fp32 (refine)
      hseqb[(size_t)t * HDIM + r0 + tid] = f2bf(hn);        // bf16 (GEMM A)
    }
  }
}

// ---------------- logits GEMM (bf16 MFMA): [256,1024] @ out_w[32000,1024]^T + out_b ----------------
__global__ __launch_bounds__(256) void k_gemm(
    const unsigned short* __restrict__ Abf, const float* __restrict__ outw,
    const float* __restrict__ outb, float* __restrict__ out) {
  const int tid  = threadIdx.x;
  const int lane = tid & 63;
  const int wv   = tid >> 6;
  const int n0   = blockIdx.x * 128;
  const int rA   = lane & 15;
  const int kg   = lane >> 4;

  f32x4 acc[4][8];
  #pragma unroll
  for (int i = 0; i < 4; i++)
    #pragma unroll
    for (int j = 0; j < 8; j++) acc[i][j] = (f32x4){0.f, 0.f, 0.f, 0.f};

  const int mbase = wv * 64 + rA;

  for (int k0 = 0; k0 < HDIM; k0 += 32) {
    const int ks = k0 + kg * 8;
    short8 afr[4];
    #pragma unroll
    for (int i = 0; i < 4; i++)
      afr[i] = *(const short8*)(Abf + (size_t)(mbase + i * 16) * HDIM + ks);

    short8 bfr[8];
    #pragma unroll
    for (int j = 0; j < 8; j++) {
      const float* bp = outw + (size_t)(n0 + j * 16 + rA) * HDIM + ks;
      float4 b0 = *(const float4*)(bp);
      float4 b1 = *(const float4*)(bp + 4);
      short8 s;
      s[0] = (short)f2bf_fast(b0.x); s[1] = (short)f2bf_fast(b0.y);
      s[2] = (short)f2bf_fast(b0.z); s[3] = (short)f2bf_fast(b0.w);
      s[4] = (short)f2bf_fast(b1.x); s[5] = (short)f2bf_fast(b1.y);
      s[6] = (short)f2bf_fast(b1.z); s[7] = (short)f2bf_fast(b1.w);
      bfr[j] = s;
    }

    #pragma unroll
    for (int i = 0; i < 4; i++)
      #pragma unroll
      for (int j = 0; j < 8; j++)
        acc[i][j] = __builtin_amdgcn_mfma_f32_16x16x32_bf16(afr[i], bfr[j], acc[i][j], 0, 0, 0);
  }

  float bias[8];
  #pragma unroll
  for (int j = 0; j < 8; j++) bias[j] = outb[n0 + j * 16 + rA];
  #pragma unroll
  for (int i = 0; i < 4; i++) {
    #pragma unroll
    for (int j = 0; j < 8; j++) {
      #pragma unroll
      for (int r = 0; r < 4; r++) {
        int m = wv * 64 + i * 16 + kg * 4 + r;
        out[(size_t)m * VDIM + n0 + j * 16 + rA] = acc[i][j][r] + bias[j];
      }
    }
  }
}

// ---------------- argmax with fp32 refinement ----------------
__global__ __launch_bounds__(256) void k_argmax(const float* __restrict__ logits,
                                                const float* __restrict__ hseqf,
                                                const float* __restrict__ outw,
                                                const float* __restrict__ outb,
                                                float* __restrict__ outids) {
  const int t = blockIdx.x;
  const int tid = threadIdx.x;
  const float* row = logits + (size_t)t * VDIM;

  float mx = -3.4e38f;
  for (int v = tid; v < VDIM; v += 256) mx = fmaxf(mx, row[v]);
  __shared__ float sm[256];
  sm[tid] = mx;
  __syncthreads();
  for (int s = 128; s > 0; s >>= 1) {
    if (tid < s) sm[tid] = fmaxf(sm[tid], sm[tid + s]);
    __syncthreads();
  }
  const float bmax = sm[0];
  __syncthreads();

  __shared__ int cand[64];
  __shared__ int cnt;
  if (tid == 0) cnt = 0;
  __syncthreads();
  const float cut = bmax - 0.25f;
  for (int v = tid; v < VDIM; v += 256) {
    if (row[v] >= cut) {
      int p = atomicAdd(&cnt, 1);
      if (p < 64) cand[p] = v;
    }
  }
  __syncthreads();
  int n = cnt < 64 ? cnt : 64;

  __shared__ float cval[64];
  if (tid < n) {
    int v = cand[tid];
    const float* w = outw + (size_t)v * HDIM;
    const float* h = hseqf + (size_t)t * HDIM;
    float s0 = 0.f, s1 = 0.f, s2 = 0.f, s3 = 0.f;
    for (int k = 0; k < HDIM; k += 4) {
      float4 wf = *(const float4*)(w + k);
      float4 hf = *(const float4*)(h + k);
      s0 += wf.x * hf.x; s1 += wf.y * hf.y; s2 += wf.z * hf.z; s3 += wf.w * hf.w;
    }
    cval[tid] = (s0 + s1) + (s2 + s3) + outb[v];
  }
  __syncthreads();
  if (tid == 0) {
    float best = -3.4e38f; int bi = 0x7FFFFFFF;
    for (int i = 0; i < n; i++) {
      float v = cval[i]; int id = cand[i];
      if (v > best || (v == best && id < bi)) { best = v; bi = id; }
    }
    outids[t] = (float)bi;
  }
}

// ---------------- launch ----------------
extern "C" void kernel_launch(void* const* d_in, const int* in_sizes, int n_in,
                              void* d_out, int out_size, void* d_ws, size_t ws_size,
                              hipStream_t stream) {
  (void)in_sizes; (void)n_in; (void)out_size; (void)ws_size;
  const float* enc    = (const float*)d_in[0];
  const int*   tokens = (const int*)d_in[1];
  const float* emb    = (const float*)d_in[2];
  const float* wzx_w  = (const float*)d_in[3];
  const float* wzx_b  = (const float*)d_in[4];
  const float* wrx_w  = (const float*)d_in[5];
  const float* wrx_b  = (const float*)d_in[6];
  const float* whx_w  = (const float*)d_in[7];
  const float* whx_b  = (const float*)d_in[8];
  const float* wzh_w  = (const float*)d_in[9];
  const float* wzh_b  = (const float*)d_in[10];
  const float* wrh_w  = (const float*)d_in[11];
  const float* wrh_b  = (const float*)d_in[12];
  const float* whh_w  = (const float*)d_in[13];
  const float* whh_b  = (const float*)d_in[14];
  const float* out_w  = (const float*)d_in[15];
  const float* out_b  = (const float*)d_in[16];
  float* ws  = (float*)d_ws;
  float* out = (float*)d_out;

  k_init<<<dim3(T_STEPS + 2), dim3(256), 0, stream>>>(enc, ws);
  k_xproj<<<dim3(192), dim3(256), 0, stream>>>(tokens, emb, wzx_w, wrx_w, whx_w,
                                               wzx_b, wzh_b, wrx_b, wrh_b, whx_b, whh_b, ws);
  k_recur<<<dim3(RG), dim3(256), 0, stream>>>(wzh_w, wrh_w, whh_w, ws);
  k_gemm<<<dim3(VDIM / 128), dim3(256), 0, stream>>>((const unsigned short*)(ws + WS_HSEQB),
                                                     out_w, out_b, out);
  k_argmax<<<dim3(T_STEPS), dim3(256), 0, stream>>>(out, ws + WS_HSEQ, out_w, out_b,
                                                    out + (size_t)T_STEPS * VDIM);
}